// Round 8
// baseline (264.713 us; speedup 1.0000x reference)
//
#include <hip/hip_runtime.h>

typedef _Float16 half8 __attribute__((ext_vector_type(8)));
typedef float f32x16 __attribute__((ext_vector_type(16)));

#define NATOMS 40000
#define D_AEV  384

constexpr int S_NUM = 4, E_NUM = 8;
constexpr int H1W = 160, H2W = 128, H3W = 96;
constexpr float ALPHA = 0.1f;
constexpr int HBLK = (NATOMS + 255) / 256;   // 157 histogram blocks
constexpr int NA2C = 40576;                  // padded sorted-atom capacity (317*128)
constexpr int NPB  = 512;                    // persistent blocks

// ---- workspace layout (bytes) ----
constexpr size_t OFF_CNT    = 0;
constexpr size_t OFF_BC     = 256;
constexpr size_t OFF_BOFF   = OFF_BC + (size_t)HBLK * S_NUM * 4;
constexpr size_t OFF_BUCKET = (OFF_BOFF + (size_t)HBLK * S_NUM * 4 + 255) & ~(size_t)255;
constexpr size_t OFF_PART   = OFF_BUCKET + (size_t)S_NUM * NATOMS * 4;
constexpr size_t OFF_WT1    = (OFF_PART + (size_t)NPB * 4 + 255) & ~(size_t)255;
constexpr size_t OFF_WT2    = OFF_WT1 + (size_t)S_NUM * E_NUM * H1W * D_AEV * 2;
constexpr size_t OFF_WT3    = OFF_WT2 + (size_t)S_NUM * E_NUM * H2W * H1W * 2;
constexpr size_t OFF_AEVS   = (OFF_WT3 + (size_t)S_NUM * E_NUM * H3W * H2W * 2 + 255) & ~(size_t)255;
constexpr size_t OFF_BIASP  = OFF_AEVS + (size_t)48 * NA2C * 8 * 2;   // + 31.2MB
// biasp: 32 * 480 floats

// ---------------- helpers ----------------

__device__ __forceinline__ void gload_lds16(const _Float16* g, _Float16* l) {
    __builtin_amdgcn_global_load_lds((const __attribute__((address_space(1))) void*)g,
                                     (__attribute__((address_space(3))) void*)l, 16, 0, 0);
}

#define VMW(n) asm volatile("s_waitcnt vmcnt(" #n ")" ::: "memory")
#define BARR() do { asm volatile("" ::: "memory"); __builtin_amdgcn_s_barrier(); \
                    asm volatile("" ::: "memory"); } while (0)

__device__ __forceinline__ float celu_f(float x) {
    return x > 0.f ? x : fmaf(ALPHA, __expf(x * (1.f / ALPHA)), -ALPHA);
}

__device__ __forceinline__ unsigned pk2(float a, float b) {
    auto p = __builtin_amdgcn_cvt_pkrtz(a, b);
    unsigned u; __builtin_memcpy(&u, &p, 4); return u;
}

template <int NL>
__device__ __forceinline__ void stage(const _Float16* we, const int* vo, int c0, _Float16* buf) {
#pragma unroll
    for (int it = 0; it < NL; ++it)
        gload_lds16(we + vo[it] + c0, buf + ((size_t)threadIdx.x + it * 256) * 8);
}

template <int OUTW, int KS16, int NFT>
__device__ __forceinline__ void consume32(const _Float16* buf, const half8* bf,
                                          f32x16* acc, int l31, int lhi) {
    __builtin_amdgcn_s_setprio(1);
#pragma unroll
    for (int t = 0; t < KS16; ++t) {
        half8 b = bf[t];
#pragma unroll
        for (int f = 0; f < NFT; ++f) {
            half8 a = *(const half8*)&buf[(((2 * t + lhi) * OUTW) + f * 32 + l31) * 8];
            acc[f] = __builtin_amdgcn_mfma_f32_32x32x16_f16(a, b, acc[f], 0, 0, 0);
        }
    }
    __builtin_amdgcn_s_setprio(0);
}

// bias+celu then cross-lhi repack: out[i] covers feats [16i + lhi*8, +8) of lane's atom
template <int NFT>
__device__ __forceinline__ void epilogue(const f32x16* acc, const float* LB, int boff,
                                         int lhi, half8* out) {
#pragma unroll
    for (int f = 0; f < NFT; ++f) {
        float val[16];
#pragma unroll
        for (int rb = 0; rb < 4; ++rb) {
            float4 bb = *(const float4*)&LB[boff + f * 32 + rb * 8 + lhi * 4];
#pragma unroll
            for (int j = 0; j < 4; ++j)
                val[rb * 4 + j] = celu_f(acc[f][rb * 4 + j] + ((const float*)&bb)[j]);
        }
        unsigned wrd[8], xw[8];
#pragma unroll
        for (int i = 0; i < 8; ++i) wrd[i] = pk2(val[2 * i], val[2 * i + 1]);
#pragma unroll
        for (int i = 0; i < 8; ++i) xw[i] = __shfl_xor(wrd[i], 32);
        unsigned f0[4], f1[4];
#pragma unroll
        for (int i = 0; i < 2; ++i) {
            f0[i]     = lhi ? xw[2 + i]  : wrd[i];
            f0[2 + i] = lhi ? wrd[2 + i] : xw[i];
            f1[i]     = lhi ? xw[6 + i]  : wrd[4 + i];
            f1[2 + i] = lhi ? wrd[6 + i] : xw[4 + i];
        }
        __builtin_memcpy(&out[2 * f], f0, 16);
        __builtin_memcpy(&out[2 * f + 1], f1, 16);
    }
}

// ---------------- pre-kernels ----------------

__global__ void hist_kernel(const int* __restrict__ species, int* __restrict__ bc) {
    __shared__ int h[S_NUM];
    int t = threadIdx.x;
    if (t < S_NUM) h[t] = 0;
    __syncthreads();
    int i = blockIdx.x * 256 + t;
    if (i < NATOMS) atomicAdd(&h[species[i]], 1);
    __syncthreads();
    if (t < S_NUM) bc[blockIdx.x * S_NUM + t] = h[t];
}

__global__ void scan_kernel(const int* __restrict__ bc, int* __restrict__ boff,
                            int* __restrict__ counts) {
    int w = threadIdx.x >> 6;
    int l = threadIdx.x & 63;
    int run = 0;
    for (int r = 0; r < (HBLK + 63) / 64; ++r) {
        int b = r * 64 + l;
        int v = (b < HBLK) ? bc[b * S_NUM + w] : 0;
        int x = v;
#pragma unroll
        for (int d = 1; d < 64; d <<= 1) { int y = __shfl_up(x, d); if (l >= d) x += y; }
        if (b < HBLK) boff[b * S_NUM + w] = run + x - v;
        run += __shfl(x, 63);
    }
    if (l == 0) counts[w] = run;
}

__global__ void scatter_kernel(const int* __restrict__ species, const int* __restrict__ boff,
                               int* __restrict__ bucket) {
    __shared__ int h[S_NUM];
    int t = threadIdx.x;
    if (t < S_NUM) h[t] = 0;
    __syncthreads();
    int i = blockIdx.x * 256 + t;
    if (i < NATOMS) {
        int sp = species[i];
        int r = atomicAdd(&h[sp], 1);
        bucket[sp * NATOMS + boff[blockIdx.x * S_NUM + sp] + r] = i;
    }
}

// sorted + k-grouped fp16 copy of aev: aevs[(g*NA2C + a2)*8 + j], a2 = sorted-padded atom
__global__ void cvt_sort_kernel(const float* __restrict__ aev, const int* __restrict__ bucket,
                                const int* __restrict__ counts, _Float16* __restrict__ aevs) {
    int a2 = blockIdx.x * 256 + threadIdx.x;
    int g = blockIdx.y;
    if (a2 >= NA2C) return;
    int c0 = counts[0], c1 = counts[1], c2 = counts[2], c3 = counts[3];
    int m0 = ((c0 + 127) >> 7) << 7;
    int m1 = m0 + (((c1 + 127) >> 7) << 7);
    int m2 = m1 + (((c2 + 127) >> 7) << 7);
    int m3 = m2 + (((c3 + 127) >> 7) << 7);
    if (a2 >= m3) return;
    int s, P, cnt;
    if (a2 < m0)      { s = 0; P = 0;  cnt = c0; }
    else if (a2 < m1) { s = 1; P = m0; cnt = c1; }
    else if (a2 < m2) { s = 2; P = m1; cnt = c2; }
    else              { s = 3; P = m2; cnt = c3; }
    int local = a2 - P;
    half8 h = (half8)(_Float16)0.f;
    if (local < cnt) {
        int aidx = bucket[s * NATOMS + local];
        const float* r = aev + (size_t)aidx * D_AEV + g * 8;
        float4 f0 = *(const float4*)r;
        float4 f1 = *(const float4*)(r + 4);
        h[0] = (_Float16)f0.x; h[1] = (_Float16)f0.y; h[2] = (_Float16)f0.z; h[3] = (_Float16)f0.w;
        h[4] = (_Float16)f1.x; h[5] = (_Float16)f1.y; h[6] = (_Float16)f1.z; h[7] = (_Float16)f1.w;
    }
    *(half8*)&aevs[((size_t)g * NA2C + a2) * 8] = h;
}

// W transpose (fp32 [out... [R][C] -> [C][R] fp16) + bias packing (z==96 path)
__global__ void transpose_all(const float* __restrict__ W1, const float* __restrict__ W2,
                              const float* __restrict__ W3,
                              const float* __restrict__ b1, const float* __restrict__ b2,
                              const float* __restrict__ b3, const float* __restrict__ w4,
                              _Float16* __restrict__ wt1, _Float16* __restrict__ wt2,
                              _Float16* __restrict__ wt3, float* __restrict__ biasp) {
    int z = blockIdx.z;
    if (z == 96) {
        if (blockIdx.x || blockIdx.y) return;
        int tid = threadIdx.y * 32 + threadIdx.x;
        for (int u = tid; u < 32 * 480; u += 256) {
            int se = u / 480, o = u % 480;
            float v;
            if (o < 160)      v = b1[se * H1W + o];
            else if (o < 288) v = b2[se * H2W + (o - 160)];
            else if (o < 384) v = b3[se * H3W + (o - 288)];
            else              v = w4[se * H3W + (o - 384)];
            biasp[u] = v;
        }
        return;
    }
    __shared__ float t[32][33];
    int m = z & 31;
    const float* src; _Float16* dst; int R, C;
    if (z < 32)      { src = W1; dst = wt1; R = D_AEV; C = H1W; }
    else if (z < 64) { src = W2; dst = wt2; R = H1W;  C = H2W; }
    else             { src = W3; dst = wt3; R = H2W;  C = H3W; }
    int c0 = blockIdx.x * 32, r0 = blockIdx.y * 32;
    if (c0 >= C || r0 >= R) return;
    src += (size_t)m * R * C;
    dst += (size_t)m * R * C;
    int tx = threadIdx.x, ty = threadIdx.y;
#pragma unroll
    for (int j = 0; j < 32; j += 8)
        t[ty + j][tx] = src[(size_t)(r0 + ty + j) * C + c0 + tx];
    __syncthreads();
#pragma unroll
    for (int j = 0; j < 32; j += 8)
        dst[(size_t)(c0 + ty + j) * R + r0 + tx] = (_Float16)t[tx][ty + j];
}

// ---------------- main persistent MLP kernel ----------------

struct Item {
    const _Float16* w1; const _Float16* w2; const _Float16* w3;
    const float* bp;           // packed bias src (global)
    const _Float16* xb;        // per-lane X base in aevs
    int vlim;                  // P_s + cnt_s  (atom validity limit)
    int a2lane;                // this lane's sorted atom position
};

#define XLOAD(dst, xb, c) do { \
    dst[0] = *(const half8*)((xb) + ((size_t)((c) * 8 + 0 + lhi) * NA2C) * 8); \
    dst[1] = *(const half8*)((xb) + ((size_t)((c) * 8 + 2 + lhi) * NA2C) * 8); \
    dst[2] = *(const half8*)((xb) + ((size_t)((c) * 8 + 4 + lhi) * NA2C) * 8); \
    dst[3] = *(const half8*)((xb) + ((size_t)((c) * 8 + 6 + lhi) * NA2C) * 8); } while (0)

__global__ void __launch_bounds__(256, 2)
mlp_main(const int* __restrict__ counts, const _Float16* __restrict__ aevs,
         const _Float16* __restrict__ wt1, const _Float16* __restrict__ wt2,
         const _Float16* __restrict__ wt3, const float* __restrict__ biasp,
         float* __restrict__ partials) {
    __shared__ __align__(16) _Float16 WB[3][8 * H1W * 8];   // 3 x 20KB
    __shared__ __align__(16) float biasL[2][1024];          // 8KB double-buffered
    __shared__ float part[4];

    const int bid = blockIdx.x;
    const int tid = threadIdx.x;
    const int l = tid & 63, w = tid >> 6;
    const int l31 = l & 31, lhi = l >> 5;
    _Float16* B0 = WB[0]; _Float16* B1 = WB[1]; _Float16* B2 = WB[2];

    const int c0 = counts[0], c1 = counts[1], c2 = counts[2], c3 = counts[3];
    const int n0 = (c0 + 127) >> 7, n1 = (c1 + 127) >> 7, n2 = (c2 + 127) >> 7, n3 = (c3 + 127) >> 7;
    const int m0 = n0, m1 = n0 + n1, m2 = m1 + n2, NT = m2 + n3;
    const int NITEMS = NT * 8;
    if (bid >= NITEMS) { if (tid == 0) partials[bid] = 0.f; return; }

    // staging source offsets
    int vo1[5], vo2a[4], vo3a[3], vo3b[2];
#pragma unroll
    for (int it = 0; it < 5; ++it) { int u = tid + it * 256; vo1[it] = (u % H1W) * D_AEV + (u / H1W) * 8; }
#pragma unroll
    for (int it = 0; it < 4; ++it) { int u = tid + it * 256; vo2a[it] = (u & 127) * H1W + (u >> 7) * 8; }
#pragma unroll
    for (int it = 0; it < 3; ++it) { int u = tid + it * 256; vo3a[it] = (u % H3W) * H2W + (u / H3W) * 8; }
#pragma unroll
    for (int it = 0; it < 2; ++it) { int u = tid + it * 256; vo3b[it] = (u < 384) ? (u % H3W) * H2W + (u / H3W) * 8 : 0; }
    const int biasoff = (tid < 120 ? tid : 119) * 8;   // halfs

    auto decode = [&](int it) {
        Item I;
        int e = it & 7, t = it >> 3;
        int s, P, cnt;
        if (t < m0)      { s = 0; P = 0;        cnt = c0; }
        else if (t < m1) { s = 1; P = m0 * 128; cnt = c1; }
        else if (t < m2) { s = 2; P = m1 * 128; cnt = c2; }
        else             { s = 3; P = m2 * 128; cnt = c3; }
        int se = s * E_NUM + e;
        I.w1 = wt1 + (size_t)se * (H1W * D_AEV);
        I.w2 = wt2 + (size_t)se * (H2W * H1W);
        I.w3 = wt3 + (size_t)se * (H3W * H2W);
        I.bp = biasp + se * 480;
        I.a2lane = t * 128 + w * 32 + l31;
        I.xb = aevs + (size_t)I.a2lane * 8;
        I.vlim = P + cnt;
        return I;
    };

    float wacc = 0.f;
    half8 xv0[4], xv1[4], xv2[4];
    half8 h1f[10], h2f[8];

    Item cur = decode(bid);
    // prologue: c0 + X0 + bias -> slot0 ; c1 + X1
    stage<5>(cur.w1, vo1, 0, B0);
    XLOAD(xv0, cur.xb, 0);
    gload_lds16((const _Float16*)cur.bp + biasoff, (_Float16*)&biasL[0][0] + tid * 8);
    stage<5>(cur.w1, vo1, 64, B1);
    XLOAD(xv1, cur.xb, 1);

    int ip = 0;

#pragma unroll 1
    for (int it = bid; it < NITEMS; it += NPB) {
        int itn = it + NPB;
        bool hn = itn < NITEMS;
        Item nxt = hn ? decode(itn) : cur;
        const float* LB = &biasL[ip][0];
        float* LBn = &biasL[ip ^ 1][0];

        f32x16 c1a[5], c2a[4], c3a[3];
#pragma unroll
        for (int f = 0; f < 5; ++f) c1a[f] = (f32x16)(0.f);
#pragma unroll
        for (int f = 0; f < 4; ++f) c2a[f] = (f32x16)(0.f);
#pragma unroll
        for (int f = 0; f < 3; ++f) c3a[f] = (f32x16)(0.f);

        // p0..p3 : W1 c2..c5
        stage<5>(cur.w1, vo1, 128, B2); XLOAD(xv2, cur.xb, 2);
        VMW(18); BARR(); consume32<H1W, 4, 5>(B0, xv0, c1a, l31, lhi); BARR();
        stage<5>(cur.w1, vo1, 192, B0); XLOAD(xv0, cur.xb, 3);
        VMW(18); BARR(); consume32<H1W, 4, 5>(B1, xv1, c1a, l31, lhi); BARR();
        stage<5>(cur.w1, vo1, 256, B1); XLOAD(xv1, cur.xb, 4);
        VMW(18); BARR(); consume32<H1W, 4, 5>(B2, xv2, c1a, l31, lhi); BARR();
        stage<5>(cur.w1, vo1, 320, B2); XLOAD(xv2, cur.xb, 5);
        VMW(18); BARR(); consume32<H1W, 4, 5>(B0, xv0, c1a, l31, lhi); BARR();
        // p4, p5 : W2 c0, c1
        stage<4>(cur.w2, vo2a, 0, B0);
        VMW(13); BARR(); consume32<H1W, 4, 5>(B1, xv1, c1a, l31, lhi); BARR();
        stage<4>(cur.w2, vo2a, 64, B1);
        VMW(8); BARR(); consume32<H1W, 4, 5>(B2, xv2, c1a, l31, lhi); BARR();

        epilogue<5>(c1a, LB, 0, lhi, h1f);

        // p6..p8 : L2
        stage<2>(cur.w2, vo2a, 128, B2);
        VMW(6); BARR(); consume32<H2W, 4, 4>(B0, &h1f[0], c2a, l31, lhi); BARR();
        stage<3>(cur.w3, vo3a, 0, B0);
        VMW(5); BARR(); consume32<H2W, 4, 4>(B1, &h1f[4], c2a, l31, lhi); BARR();
        stage<2>(cur.w3, vo3b, 64, B1);
        VMW(5); BARR(); consume32<H2W, 2, 4>(B2, &h1f[8], c2a, l31, lhi); BARR();

        epilogue<4>(c2a, LB, 160, lhi, h2f);

        // p9..p11 : L3 (+ next-item prefetch)
        stage<2>(cur.w3, vo3b, 96, B2);
        VMW(4); BARR(); consume32<H3W, 4, 3>(B0, &h2f[0], c3a, l31, lhi); BARR();
        if (hn) {
            stage<5>(nxt.w1, vo1, 0, B0); XLOAD(xv0, nxt.xb, 0);
            gload_lds16((const _Float16*)nxt.bp + biasoff, (_Float16*)LBn + tid * 8);
            VMW(12);
        } else { VMW(2); }
        BARR(); consume32<H3W, 2, 3>(B1, &h2f[4], c3a, l31, lhi); BARR();
        if (hn) {
            stage<5>(nxt.w1, vo1, 64, B1); XLOAD(xv1, nxt.xb, 1);
            VMW(19);
        } else { VMW(0); }
        BARR(); consume32<H3W, 2, 3>(B2, &h2f[6], c3a, l31, lhi); BARR();

        // L3 epilogue: dot with w4
        {
            float pe = 0.f;
#pragma unroll
            for (int f = 0; f < 3; ++f) {
#pragma unroll
                for (int rb = 0; rb < 4; ++rb) {
                    float4 bb = *(const float4*)&LB[288 + f * 32 + rb * 8 + lhi * 4];
                    float4 ww = *(const float4*)&LB[384 + f * 32 + rb * 8 + lhi * 4];
#pragma unroll
                    for (int j = 0; j < 4; ++j)
                        pe += celu_f(c3a[f][rb * 4 + j] + ((const float*)&bb)[j]) * ((const float*)&ww)[j];
                }
            }
            pe += __shfl_xor(pe, 32);
            if (lhi == 0 && cur.a2lane < cur.vlim) wacc += pe;
        }

        cur = nxt;
        ip ^= 1;
    }

    // block reduction
#pragma unroll
    for (int m = 1; m < 64; m <<= 1) wacc += __shfl_xor(wacc, m);
    if (l == 0) part[w] = wacc;
    __syncthreads();
    if (tid == 0) partials[bid] = part[0] + part[1] + part[2] + part[3];
}

// ---------------- finalize ----------------

__global__ void finalize_kernel(const float* __restrict__ partials, const int* __restrict__ counts,
                                const float* __restrict__ b4, float* __restrict__ out) {
    __shared__ float wsum[4];
    float s = 0.f;
    for (int i = threadIdx.x; i < NPB; i += 256) s += partials[i];
#pragma unroll
    for (int m = 1; m < 64; m <<= 1) s += __shfl_xor(s, m);
    if ((threadIdx.x & 63) == 0) wsum[threadIdx.x >> 6] = s;
    __syncthreads();
    if (threadIdx.x == 0) {
        float tot = wsum[0] + wsum[1] + wsum[2] + wsum[3];
        float bt = 0.f;
        for (int sp = 0; sp < S_NUM; ++sp) {
            float bs = 0.f;
            for (int e = 0; e < E_NUM; ++e) bs += b4[sp * E_NUM + e];
            bt += (float)counts[sp] * bs;
        }
        out[0] = (tot + bt) * 0.125f;
    }
}

// ---------------- launcher ----------------

extern "C" void kernel_launch(void* const* d_in, const int* in_sizes, int n_in,
                              void* d_out, int out_size, void* d_ws, size_t ws_size,
                              hipStream_t stream) {
    const int*   species = (const int*)d_in[0];
    const float* aev = (const float*)d_in[1];
    const float* W1 = (const float*)d_in[2];
    const float* b1 = (const float*)d_in[3];
    const float* W2 = (const float*)d_in[4];
    const float* b2 = (const float*)d_in[5];
    const float* W3 = (const float*)d_in[6];
    const float* b3 = (const float*)d_in[7];
    const float* W4 = (const float*)d_in[8];
    const float* b4 = (const float*)d_in[9];
    float* out = (float*)d_out;

    char* ws = (char*)d_ws;
    int* counts = (int*)(ws + OFF_CNT);
    int* bc     = (int*)(ws + OFF_BC);
    int* boff   = (int*)(ws + OFF_BOFF);
    int* bucket = (int*)(ws + OFF_BUCKET);
    float* partials = (float*)(ws + OFF_PART);
    _Float16* wt1 = (_Float16*)(ws + OFF_WT1);
    _Float16* wt2 = (_Float16*)(ws + OFF_WT2);
    _Float16* wt3 = (_Float16*)(ws + OFF_WT3);
    _Float16* aevs = (_Float16*)(ws + OFF_AEVS);
    float* biasp = (float*)(ws + OFF_BIASP);

    hist_kernel<<<HBLK, 256, 0, stream>>>(species, bc);
    scan_kernel<<<1, 256, 0, stream>>>(bc, boff, counts);
    scatter_kernel<<<HBLK, 256, 0, stream>>>(species, boff, bucket);
    transpose_all<<<dim3(5, 12, 97), dim3(32, 8), 0, stream>>>(W1, W2, W3, b1, b2, b3, W4,
                                                               wt1, wt2, wt3, biasp);
    cvt_sort_kernel<<<dim3((NA2C + 255) / 256, 48), 256, 0, stream>>>(aev, bucket, counts, aevs);

    mlp_main<<<NPB, 256, 0, stream>>>(counts, aevs, wt1, wt2, wt3, biasp, partials);

    finalize_kernel<<<1, 256, 0, stream>>>(partials, counts, b4, out);
}